// Round 15
// baseline (809.588 us; speedup 1.0000x reference)
//
#include <hip/hip_runtime.h>
#include <hip/hip_bf16.h>
#include <stdint.h>

// Problem constants (from reference)
#define IN_F 4096
#define OUT_F 11008
#define M_ROWS 8192              // 4 * 2048
#define NIG 512                  // IN_FEATURES / IN_GROUP(8)
#define CBSZ 256

typedef _Float16 f16x8 __attribute__((ext_vector_type(8)));
typedef float f32x4 __attribute__((ext_vector_type(4)));
typedef float f32x16 __attribute__((ext_vector_type(16)));

// ---------------------------------------------------------------------------
// Kernel 1: dequantize W (UNSCALED: scales applied in GEMM epilogue in fp32).
// ---------------------------------------------------------------------------
__global__ __launch_bounds__(256) void dequant_w_kernel(
    const int* __restrict__ codes, const float* __restrict__ cbs,
    _Float16* __restrict__ W)
{
  const int idx = blockIdx.x * 256 + threadIdx.x;   // o*512 + g (exact grid)
  const int2 c = ((const int2*)codes)[idx];
  const float4* e0 = (const float4*)(cbs + (size_t)c.x * 8);
  const float4* e1 = (const float4*)(cbs + (size_t)CBSZ * 8 + (size_t)c.y * 8);
  const float4 a0 = e0[0], a1 = e0[1];
  const float4 b0 = e1[0], b1 = e1[1];
  f16x8 w;
  w[0] = (_Float16)(a0.x + b0.x);
  w[1] = (_Float16)(a0.y + b0.y);
  w[2] = (_Float16)(a0.z + b0.z);
  w[3] = (_Float16)(a0.w + b0.w);
  w[4] = (_Float16)(a1.x + b1.x);
  w[5] = (_Float16)(a1.y + b1.y);
  w[6] = (_Float16)(a1.z + b1.z);
  w[7] = (_Float16)(a1.w + b1.w);
  *(f16x8*)(W + (size_t)idx * 8) = w;
}

// ---------------------------------------------------------------------------
// Kernel 2: x fp32 -> f16, 8 elems/thread, vectorized.
// ---------------------------------------------------------------------------
__global__ __launch_bounds__(256) void convert_x_kernel(
    const float* __restrict__ x, _Float16* __restrict__ X)
{
  const size_t i = ((size_t)blockIdx.x * 256 + threadIdx.x) * 8;
  const float4 a = *(const float4*)(x + i);
  const float4 b = *(const float4*)(x + i + 4);
  f16x8 v;
  v[0] = (_Float16)a.x; v[1] = (_Float16)a.y;
  v[2] = (_Float16)a.z; v[3] = (_Float16)a.w;
  v[4] = (_Float16)b.x; v[5] = (_Float16)b.y;
  v[6] = (_Float16)b.z; v[7] = (_Float16)b.w;
  *(f16x8*)(X + i) = v;
}

// ---------------------------------------------------------------------------
// Kernel 3: 256x256x64 f16 GEMM — 32x32x16 MFMA (shape lever).
//
// WHY (r6..r14): seven schedules all plateau at MfmaUtil 42-46%; the residual
// is NOT schedule-movable at source level. 32x32x16 vs 16x16x32 at equal
// FLOP: +15% pipe ceiling (2382 vs 2075 TF ubench), HALF the MFMA insts
// (32 vs 64/wave/tile), same LDS bytes & ds_read count, same 128-reg acc.
// MFMA floor/tile: 2484 -> 2163 cy.
//
// Fragment mapping (32x32x16 f16): A row=lane&31, k=(lane>>5)*8+j; B
// col=lane&31 (W-row), same k; C/D col=lane&31, row=(reg&3)+8*(reg>>2)+
// 4*(lane>>5) [m74/m101 HW-verified, dtype-independent].
//
// LDS image UNCHANGED from r9 (same [256][64] f16, chunk_lds = chunk ^
// (row&7), staging pre-permutes global col, dest linear). Read offset for
// k-step ks (16 k): byte = row*128 + (((2*ks + q2) ^ (lane&7)) << 4),
// q2 = lane>>5. Quarter-wave: lanes 0-15 = rows 0-15 -> 2 rows/16B-chunk
// -> 2 lanes/bank = free (same model that measured 0 conflicts).
//
// Schedule per tile t (parity P; 4 phases = 4 k-steps; 1 BAR each):
//   ph1: stg A(t+1)c01 -> bufA[1-P] | rd B(t) ALL 8 frags + A ks0 | MFMA ks0
//   ph2: stg A(t+1)c23             | rd A ks1                    | MFMA ks1
//   ph3: stg B(t+2)c01 -> bufB[P]  | rd A ks2                    | MFMA ks2
//   ph4: stg B(t+2)c23             | rd A ks3                    | MFMA ks3
//        gate vmcnt(4); BAR
// B front-loaded in ph1 => bufB[P]'s reads all retire before end-ph1 BAR =>
// B(t+2) staging at ph3 (2 barriers later) is WAR-safe. A(t+1)->bufA[1-P]:
// last reads (t-1 ph4) retired before end-ph4(t-1) BAR => ph1 stage safe.
// Ledger (per-thread, steady): entering ph1(t): outstanding = B(t+1)x4.
// +A(t+1)x4 (ph1-2), +B(t+2)x4 (ph3-4) -> 12; vmcnt(4) retires B(t+1),
// A(t+1) (older) -> leaves B(t+2)x4. Floor 4; drain only at t=62.
// ---------------------------------------------------------------------------
#define BM 256
#define BN 256
#define BK 64
#define NKT (IN_F / BK)          // 64
#define GRID_MT (M_ROWS / BM)    // 32
#define GRID_NT (OUT_F / BN)     // 43

__global__ __launch_bounds__(512, 2) void gemm_pipe(
    const _Float16* __restrict__ X, const _Float16* __restrict__ Wd,
    const float* __restrict__ scales, const float* __restrict__ bias,
    float* __restrict__ out)
{
  __shared__ char smem[131072];  // [2 bufs][A 32KB | B 32KB]

  // T1: XCD swizzle; nwg = 1376 % 8 == 0 -> simple form bijective
  const int cpx = (GRID_MT * GRID_NT) >> 3;        // 172
  const int wg = (blockIdx.x & 7) * cpx + (blockIdx.x >> 3);
  const int mt = wg & (GRID_MT - 1), nt = wg >> 5; // m-inner: same B-panel per XCD
  const int m0 = mt * BM, n0 = nt * BN;

  const int t_ = threadIdx.x;
  const int wave = t_ >> 6, lane = t_ & 63;
  const int wm = wave >> 2, wn = wave & 3;
  const int r32 = lane & 31;
  const int q2 = lane >> 5;                        // k-half within 16-k step
  const int sw = lane & 7;                         // row&7 (rows offset by mult of 32)
  const int ck0 = (((0 + q2) ^ sw) << 4);          // swizzled chunk byte, ks=0
  const int ck1 = (((2 + q2) ^ sw) << 4);          // ks=1
  const int ck2 = (((4 + q2) ^ sw) << 4);          // ks=2
  const int ck3 = (((6 + q2) ^ sw) << 4);          // ks=3

  // Staging (identical to r9; LDS image independent of MFMA shape):
  // thread t's 16B lands at linear LDS byte (call*8192 + t*16)
  //   -> row = call*64 + (t>>3), chunk_lds = t&7; logical chunk = (t&7)^((t>>3)&7)
  const int s_row0 = t_ >> 3;
  const int s_col  = (((t_ & 7) ^ ((t_ >> 3) & 7)) << 3);
  const _Float16* asrc = X  + (size_t)(m0 + s_row0) * IN_F + s_col;
  const _Float16* bsrc = Wd + (size_t)(n0 + s_row0) * IN_F + s_col;
  const int s_dst = wave * 1024;                   // wave-uniform; HW adds lane*16

  f32x16 acc[4][2] = {};                           // 128 VGPR accumulator
  f16x8 a[4];                                      // per-phase A frags (reused)
  f16x8 b[2][4];                                   // B(t): [nf][ks], live all tile

#define GLD(gsrc, ldst) __builtin_amdgcn_global_load_lds(                     \
    (const __attribute__((address_space(1))) void*)(gsrc),                    \
    (__attribute__((address_space(3))) void*)(ldst), 16, 0, 0)
#define STAGE_A(kt, bufc, i) GLD(asrc + (size_t)(kt) * BK + (size_t)(i) * 64 * IN_F, \
    smem + (bufc) * 65536 + (i) * 8192 + s_dst)
#define STAGE_B(kt, bufc, i) GLD(bsrc + (size_t)(kt) * BK + (size_t)(i) * 64 * IN_F, \
    smem + (bufc) * 65536 + 32768 + (i) * 8192 + s_dst)

#define RD_A(bufp, mf, cc) (*(const f16x8*)((bufp) + ((wm * 128 + (mf) * 32 + r32) << 7) + (cc)))
#define RD_B(bufp, nf, cc) (*(const f16x8*)((bufp) + 32768 + ((wn * 64 + (nf) * 32 + r32) << 7) + (cc)))

#define BAR   __builtin_amdgcn_s_barrier()
#define PRIO1 __builtin_amdgcn_s_setprio(1)
#define PRIO0 __builtin_amdgcn_s_setprio(0)
#define VM4 asm volatile("s_waitcnt vmcnt(4)" ::: "memory")
#define VM0 asm volatile("s_waitcnt vmcnt(0)" ::: "memory")

// 8-MFMA group for k-step ks: 4 m-frags x 2 n-frags (32x32x16 each)
#define MG(ks)                                                                \
    _Pragma("unroll")                                                         \
    for (int mf = 0; mf < 4; ++mf)                                            \
      _Pragma("unroll")                                                       \
      for (int nf = 0; nf < 2; ++nf)                                          \
        acc[mf][nf] = __builtin_amdgcn_mfma_f32_32x32x16_f16(                 \
            a[mf], b[nf][ks], acc[mf][nf], 0, 0, 0)

// One K-tile. P parity. SA: stage A(t+1). SB: stage B(t+2).
// GATE: 4 -> vmcnt(4), 0 -> vmcnt(0), -1 -> none.
#define TILE(P, tt, SA, SB, GATE) do {                                        \
    const char* bufT = smem + (P) * 65536;                                    \
    /* ph1: stg A01; rd B all 8 + A ks0; MFMA ks0 */                          \
    if (SA) { STAGE_A((tt) + 1, 1 - (P), 0); STAGE_A((tt) + 1, 1 - (P), 1); } \
    _Pragma("unroll")                                                         \
    for (int nf = 0; nf < 2; ++nf) {                                          \
      b[nf][0] = RD_B(bufT, nf, ck0); b[nf][1] = RD_B(bufT, nf, ck1);         \
      b[nf][2] = RD_B(bufT, nf, ck2); b[nf][3] = RD_B(bufT, nf, ck3);         \
    }                                                                         \
    _Pragma("unroll")                                                         \
    for (int mf = 0; mf < 4; ++mf) a[mf] = RD_A(bufT, mf, ck0);               \
    PRIO1; MG(0); PRIO0; BAR;                                                 \
    /* ph2: stg A23; rd A ks1; MFMA ks1 */                                    \
    if (SA) { STAGE_A((tt) + 1, 1 - (P), 2); STAGE_A((tt) + 1, 1 - (P), 3); } \
    _Pragma("unroll")                                                         \
    for (int mf = 0; mf < 4; ++mf) a[mf] = RD_A(bufT, mf, ck1);               \
    PRIO1; MG(1); PRIO0; BAR;                                                 \
    /* ph3: stg B(t+2)01 -> bufB[P] (B(t) reads retired 2 BARs ago); ks2 */   \
    if (SB) { STAGE_B((tt) + 2, P, 0); STAGE_B((tt) + 2, P, 1); }             \
    _Pragma("unroll")                                                         \
    for (int mf = 0; mf < 4; ++mf) a[mf] = RD_A(bufT, mf, ck2);               \
    PRIO1; MG(2); PRIO0; BAR;                                                 \
    /* ph4: stg B(t+2)23; rd A ks3; MFMA ks3; gate; publish */                \
    if (SB) { STAGE_B((tt) + 2, P, 2); STAGE_B((tt) + 2, P, 3); }             \
    _Pragma("unroll")                                                         \
    for (int mf = 0; mf < 4; ++mf) a[mf] = RD_A(bufT, mf, ck3);               \
    PRIO1; MG(3); PRIO0;                                                      \
    if ((GATE) == 4) { VM4; }                                                 \
    if ((GATE) == 0) { VM0; }                                                 \
    BAR;                                                                      \
  } while (0)

  // ---- Prologue: A(0), B(0), B(1); retire A(0)+B(0), keep B(1)x4 in flight
  STAGE_A(0, 0, 0); STAGE_A(0, 0, 1); STAGE_A(0, 0, 2); STAGE_A(0, 0, 3);
  STAGE_B(0, 0, 0); STAGE_B(0, 0, 1); STAGE_B(0, 0, 2); STAGE_B(0, 0, 3);
  STAGE_B(1, 1, 0); STAGE_B(1, 1, 1); STAGE_B(1, 1, 2); STAGE_B(1, 1, 3);
  VM4;                       // A(0),B(0) landed; B(1)x4 in flight (invariant)
  BAR;

  // ---- Main loop: tiles 0..61 full; 62 stages A(63) + drain; 63 bare
  #pragma unroll 1
  for (int t = 0; t < 62; t += 2) {
    TILE(0, t,     1, 1, 4);
    TILE(1, t + 1, 1, 1, 4);
  }
  TILE(0, 62, 1, 0, 0);      // vmcnt(0): retires A(63), B(63)
  TILE(1, 63, 0, 0, -1);

  // Epilogue: acc * scales[col] + bias[col], fp32.
  // C/D (32x32): col = lane&31, row = (reg&3) + 8*(reg>>2) + 4*q2 (m74/m101).
  #pragma unroll
  for (int nf = 0; nf < 2; ++nf) {
    const int col = n0 + wn * 64 + nf * 32 + r32;
    const float s = scales[col];
    const float bb = bias[col];
    #pragma unroll
    for (int mf = 0; mf < 4; ++mf) {
      const int rb = m0 + wm * 128 + mf * 32 + 4 * q2;
      #pragma unroll
      for (int reg = 0; reg < 16; ++reg) {
        const int row = rb + (reg & 3) + 8 * (reg >> 2);
        out[(size_t)row * OUT_F + col] = acc[mf][nf][reg] * s + bb;
      }
    }
  }
#undef TILE
#undef MG
#undef RD_A
#undef RD_B
#undef STAGE_A
#undef STAGE_B
#undef GLD
}

// ---------------------------------------------------------------------------
// Fallback (only if ws too small): correct but slow fp32 path.
// ---------------------------------------------------------------------------
__global__ __launch_bounds__(256) void naive_kernel(
    const float* __restrict__ x, const int* __restrict__ codes,
    const float* __restrict__ cbs, const float* __restrict__ scales,
    const float* __restrict__ bias, float* __restrict__ out)
{
  __shared__ float xrow[IN_F];
  const int m = blockIdx.x;
  for (int i = threadIdx.x; i < IN_F; i += 256)
    xrow[i] = x[(size_t)m * IN_F + i];
  __syncthreads();
  for (int o = threadIdx.x; o < OUT_F; o += 256) {
    float acc = 0.f;
    const int2* crow = (const int2*)codes + (size_t)o * NIG;
    for (int g = 0; g < NIG; ++g) {
      const int2 c = crow[g];
      const float* e0 = cbs + (size_t)c.x * 8;
      const float* e1 = cbs + (size_t)CBSZ * 8 + (size_t)c.y * 8;
      const float* xr = xrow + g * 8;
      #pragma unroll
      for (int j = 0; j < 8; ++j) acc += (e0[j] + e1[j]) * xr[j];
    }
    out[(size_t)m * OUT_F + o] = acc * scales[o] + bias[o];
  }
}

// ---------------------------------------------------------------------------
extern "C" void kernel_launch(void* const* d_in, const int* in_sizes, int n_in,
                              void* d_out, int out_size, void* d_ws, size_t ws_size,
                              hipStream_t stream) {
  const float* x      = (const float*)d_in[0];
  const int*   codes  = (const int*)d_in[1];
  const float* cbs    = (const float*)d_in[2];
  const float* scales = (const float*)d_in[3];
  const float* bias   = (const float*)d_in[4];
  float* out = (float*)d_out;

  const size_t W_BYTES = (size_t)OUT_F * IN_F * sizeof(_Float16);  // 90.2 MB
  const size_t X_BYTES = (size_t)M_ROWS * IN_F * sizeof(_Float16); // 67.1 MB

  if (ws_size < W_BYTES + X_BYTES) {
    naive_kernel<<<M_ROWS, 256, 0, stream>>>(x, codes, cbs, scales, bias, out);
    return;
  }

  _Float16* W = (_Float16*)d_ws;
  _Float16* X = (_Float16*)((char*)d_ws + W_BYTES);

  dequant_w_kernel<<<(OUT_F * NIG) / 256, 256, 0, stream>>>(codes, cbs, W);
  convert_x_kernel<<<(M_ROWS * IN_F / 8) / 256, 256, 0, stream>>>(x, X);
  gemm_pipe<<<GRID_MT * GRID_NT, 512, 0, stream>>>(X, W, scales, bias, out);
}